// Round 5
// baseline (107.152 us; speedup 1.0000x reference)
//
#include <hip/hip_runtime.h>

#define HH 32
#define WW 32
#define NB 16
#define NPOS 512
#define TILE 8            // output positions per block (row segment)
#define PPAD 516          // padded p-stride: 516 % 32 == 4 -> conflict-free float4 reads
#define NTHR 512          // 8 waves
#define NPA 30            // inner-layer (mid) positions: 3 rows x 10 cols
#define NPB 8             // outer-layer (output) positions
#define NPT (NPA + NPB)   // 38 staged positions

__device__ __forceinline__ void make_uv(const float c[9], float* u, float* v) {
    // v[lo] over window elems m=4..8 (MSB-first), u[hi] over m=0..3
    float a2[2], a4[4], a8[8], a16[16];
    a2[0] = 1.0f - c[4]; a2[1] = c[4];
    #pragma unroll
    for (int i = 0; i < 2; ++i)  { a4[2*i]  = a2[i]  * (1.0f - c[5]); a4[2*i+1]  = a2[i]  * c[5]; }
    #pragma unroll
    for (int i = 0; i < 4; ++i)  { a8[2*i]  = a4[i]  * (1.0f - c[6]); a8[2*i+1]  = a4[i]  * c[6]; }
    #pragma unroll
    for (int i = 0; i < 8; ++i)  { a16[2*i] = a8[i]  * (1.0f - c[7]); a16[2*i+1] = a8[i]  * c[7]; }
    #pragma unroll
    for (int i = 0; i < 16; ++i) { v[2*i]   = a16[i] * (1.0f - c[8]); v[2*i+1]   = a16[i] * c[8]; }
    float b2[2], b4[4], b8[8];
    b2[0] = 1.0f - c[0]; b2[1] = c[0];
    #pragma unroll
    for (int i = 0; i < 2; ++i) { b4[2*i] = b2[i] * (1.0f - c[1]); b4[2*i+1] = b2[i] * c[1]; }
    #pragma unroll
    for (int i = 0; i < 4; ++i) { b8[2*i] = b4[i] * (1.0f - c[2]); b8[2*i+1] = b4[i] * c[2]; }
    #pragma unroll
    for (int i = 0; i < 8; ++i) { u[2*i]  = b8[i] * (1.0f - c[3]); u[2*i+1]  = b8[i] * c[3]; }
}

__device__ __forceinline__ float lut_dot4(const float4* lut4, const float* u, const float* v,
                                          int hi0, int nhi) {
    float acc = 0.0f;
    for (int hh = 0; hh < nhi; ++hh) {
        int hi = hi0 + hh;
        float ps0 = 0.f, ps1 = 0.f, ps2 = 0.f, ps3 = 0.f;
        #pragma unroll
        for (int l4 = 0; l4 < 8; ++l4) {
            float4 L = lut4[hi * 8 + l4];
            ps0 = fmaf(L.x, v[4*l4+0], ps0);
            ps1 = fmaf(L.y, v[4*l4+1], ps1);
            ps2 = fmaf(L.z, v[4*l4+2], ps2);
            ps3 = fmaf(L.w, v[4*l4+3], ps3);
        }
        acc = fmaf(u[hi], (ps0 + ps1) + (ps2 + ps3), acc);
    }
    return acc;
}

// Two fused layers: src --(tgA)--> mid(30 pos, LDS) --(tgB)--> dst(8 pos)
__global__ __launch_bounds__(NTHR) void asic_pair(
    const float* __restrict__ src,   // (16,32,32) state before layer A
    const float* __restrict__ tgA,   // (512,32,32) gates, inner layer
    const float* __restrict__ tgB,   // (512,32,32) gates, outer layer
    float* __restrict__ dst)         // (16,32,32) state after layer B
{
    __shared__ float lutA[NPA * PPAD];   // 61.9 KB
    __shared__ float lutB[NPB * PPAD];   // 16.5 KB
    __shared__ float mid[NPA * NB];      // 1.9 KB
    __shared__ float red[NTHR];          // 2 KB

    const int t   = threadIdx.x;         // 0..511
    const int hw0 = blockIdx.x * TILE;
    const int h   = hw0 >> 5;            // tile row
    const int w0  = hw0 & 31;            // tile col start (0,8,16,24)

    // ---- stage sigmoid LUTs for 30 mid + 8 out positions (38 iters/thread)
    #pragma unroll 4
    for (int k = 0; k < NPT; ++k) {
        int f   = t + NTHR * k;          // 0..19455
        int p   = f / NPT;
        int pos = f - p * NPT;
        float g;
        float* slot;
        if (pos < NPA) {
            int i  = pos / 10;
            int jj = pos - 10 * i;
            int rm = (h + i) & 31;
            int cm = (w0 - 1 + jj + 32) & 31;
            g = tgA[p * (HH * WW) + rm * 32 + cm];
            slot = &lutA[pos * PPAD + p];
        } else {
            int pb = pos - NPA;
            int cm = w0 + pb;            // never wraps (w0<=24, pb<8)
            g = tgB[p * (HH * WW) + h * 32 + cm];
            slot = &lutB[pb * PPAD + p];
        }
        *slot = 1.0f / (1.0f + __expf(-g));
    }
    __syncthreads();

    // ---- phase A: 30 mid positions x 16 batches = 480 cells, 1 thread each
    if (t < NPA * NB) {
        int pos = t >> 4;                // 0..29  (wave = 4 pos x 16 batches: broadcast reads)
        int b   = t & 15;
        int i   = pos / 10;
        int jj  = pos - 10 * i;
        int rm  = h + i;                 // unmasked base
        int cmb = w0 - 1 + jj;           // in [-1, 33]

        float c[9];
        const float* sb = src + b * (HH * WW);
        #pragma unroll
        for (int ii = 0; ii < 3; ++ii) {
            int row = ((rm + ii) & 31) * 32;
            #pragma unroll
            for (int ji = 0; ji < 3; ++ji) {
                c[3 * ii + ji] = sb[row + ((cmb + ji - 1 + 32) & 31)];
            }
        }
        float u[16], v[32];
        make_uv(c, u, v);
        float acc = lut_dot4((const float4*)(lutA + pos * PPAD), u, v, 0, 16);
        mid[pos * NB + b] = fminf(fmaxf(acc, 0.0f), 1.0f);
    }
    __syncthreads();

    // ---- phase B: 8 out positions x 16 batches, 4 threads/cell (hi-split)
    {
        int c128 = t & 127;
        int q    = t >> 7;               // hi-quarter
        int posB = c128 >> 4;            // 0..7
        int b    = c128 & 15;

        float c[9];
        #pragma unroll
        for (int wi = 0; wi < 3; ++wi) {
            #pragma unroll
            for (int wj = 0; wj < 3; ++wj) {
                // output col w0+posB, window col offset wj-1 -> mid jj = posB+wj
                c[3 * wi + wj] = mid[(wi * 10 + posB + wj) * NB + b];
            }
        }
        float u[16], v[32];
        make_uv(c, u, v);
        float acc = lut_dot4((const float4*)(lutB + posB * PPAD), u, v, 4 * q, 4);

        red[t] = acc;
        __syncthreads();

        if (t < 128) {
            float s = (red[t] + red[t + 128]) + (red[t + 256] + red[t + 384]);
            s = fminf(fmaxf(s, 0.0f), 1.0f);
            dst[b * (HH * WW) + h * 32 + (w0 + posB)] = s;
        }
    }
}

extern "C" void kernel_launch(void* const* d_in, const int* in_sizes, int n_in,
                              void* d_out, int out_size, void* d_ws, size_t ws_size,
                              hipStream_t stream) {
    const float* x  = (const float*)d_in[0];   // (16,32,32)
    const float* tg = (const float*)d_in[1];   // (4,512,32,32)
    float* out = (float*)d_out;
    float* ws  = (float*)d_ws;                 // 64 KB used

    const int grid = (HH * WW) / TILE;         // 128 blocks
    const size_t L = (size_t)NPOS * HH * WW;

    // layers 0+1 fused, then 2+3 fused; kernel boundary = coherence point
    asic_pair<<<grid, NTHR, 0, stream>>>(x,  tg + 0 * L, tg + 1 * L, ws);
    asic_pair<<<grid, NTHR, 0, stream>>>(ws, tg + 2 * L, tg + 3 * L, out);
}

// Round 6
// 76.297 us; speedup vs baseline: 1.4044x; 1.4044x over previous
//
#include <hip/hip_runtime.h>

#define HH 32
#define WW 32
#define NPOS 512
#define TILE 8            // spatial positions per block (row segment)
#define PPAD 516          // padded p-stride: 516 % 32 == 4 -> conflict-free float4 reads
#define NTHR 256          // 4 waves; thread = (hwl:8, bpair:4, hi-oct:8), serves 2 batches x 2 hi
#define RPAD 33           // float2 stride per oct in reduction buffer (33*2 % 32 == 2)

__device__ __forceinline__ void make_v(const float c[9], float* v) {
    // v[lo] over window elems m=4..8 (MSB-first)
    float a2[2], a4[4], a8[8], a16[16];
    a2[0] = 1.0f - c[4]; a2[1] = c[4];
    #pragma unroll
    for (int i = 0; i < 2; ++i)  { a4[2*i]  = a2[i]  * (1.0f - c[5]); a4[2*i+1]  = a2[i]  * c[5]; }
    #pragma unroll
    for (int i = 0; i < 4; ++i)  { a8[2*i]  = a4[i]  * (1.0f - c[6]); a8[2*i+1]  = a4[i]  * c[6]; }
    #pragma unroll
    for (int i = 0; i < 8; ++i)  { a16[2*i] = a8[i]  * (1.0f - c[7]); a16[2*i+1] = a8[i]  * c[7]; }
    #pragma unroll
    for (int i = 0; i < 16; ++i) { v[2*i]   = a16[i] * (1.0f - c[8]); v[2*i+1]   = a16[i] * c[8]; }
}

__global__ __launch_bounds__(NTHR) void asic_layer(
    const float* __restrict__ src,   // (16,32,32) current state
    const float* __restrict__ tg,    // (512,32,32) toggle gates, this layer
    float* __restrict__ dst)         // (16,32,32) next state
{
    __shared__ float  lut[TILE * PPAD];   // 16.5 KB sigmoid LUT, shared by this block's 8 batches
    __shared__ float2 red[8 * RPAD];      // 2.1 KB partial sums (oct-major, padded)

    const int t     = threadIdx.x;        // 0..255
    const int sp    = blockIdx.x & 127;   // spatial tile
    const int bhalf = blockIdx.x >> 7;    // batch half (block i and i+128 share XCD -> share gate L2 lines)
    const int hw0   = sp * TILE;

    // ---- stage sigmoid(tg) for our 8 positions (coalesced: wave = 8 p-planes x 8 contiguous floats)
    #pragma unroll
    for (int k = 0; k < 16; ++k) {
        int f   = t + NTHR * k;           // 0..4095
        int p   = f >> 3;
        int pos = f & 7;
        float g = tg[p * (HH * WW) + hw0 + pos];
        lut[pos * PPAD + p] = 1.0f / (1.0f + __expf(-g));
    }

    const int hwl = t & 7;                // position in tile
    const int bp  = (t >> 3) & 3;         // batch pair within half
    const int oct = t >> 5;               // hi-octant: this thread does hi = 2*oct, 2*oct+1
    const int h   = hw0 >> 5;
    const int w   = (hw0 & 31) + hwl;
    const int b0  = bhalf * 8 + 2 * bp;   // first of the 2 batches

    // ---- gather 3x3 wrapped windows for both batches (before sync: overlap with staging)
    float c0[9], c1[9];
    const float* s0 = src + b0 * (HH * WW);
    const float* s1 = s0 + (HH * WW);
    #pragma unroll
    for (int i = 0; i < 3; ++i) {
        int row = ((h + i) & 31) * 32;
        #pragma unroll
        for (int j = 0; j < 3; ++j) {
            int idx = row + ((w + j - 1 + 32) & 31);
            c0[3 * i + j] = s0[idx];
            c1[3 * i + j] = s1[idx];
        }
    }

    __syncthreads();   // lut ready

    float v0[32], v1[32];
    make_v(c0, v0);
    make_v(c1, v1);

    // ---- u[hi] for hi = 2*oct(+1): direct 5-mul product (bits m=0..2 from oct MSB-first, m=3 = low bit)
    const int bit0 = (oct >> 2) & 1, bit1 = (oct >> 1) & 1, bit2 = oct & 1;
    float base0 = (bit0 ? c0[0] : 1.0f - c0[0]) * (bit1 ? c0[1] : 1.0f - c0[1]) * (bit2 ? c0[2] : 1.0f - c0[2]);
    float base1 = (bit0 ? c1[0] : 1.0f - c1[0]) * (bit1 ? c1[1] : 1.0f - c1[1]) * (bit2 ? c1[2] : 1.0f - c1[2]);
    float uA0 = base0 * (1.0f - c0[3]), uB0 = base0 * c0[3];   // batch0: hi=2oct, hi=2oct+1
    float uA1 = base1 * (1.0f - c1[3]), uB1 = base1 * c1[3];   // batch1

    // ---- dot: each lut float4 read ONCE, FMA'd for both batches (16 b128 reads, 128 FMA)
    const float4* lutp = (const float4*)(lut + hwl * PPAD);
    const float4* A = lutp + (2 * oct) * 8;
    const float4* B = A + 8;

    float sA0 = 0.f, sA1 = 0.f, sB0 = 0.f, sB1 = 0.f;
    #pragma unroll
    for (int l4 = 0; l4 < 8; ++l4) {
        float4 LA = A[l4];
        float4 LB = B[l4];
        sA0 = fmaf(LA.x, v0[4*l4+0], sA0); sA0 = fmaf(LA.y, v0[4*l4+1], sA0);
        sA0 = fmaf(LA.z, v0[4*l4+2], sA0); sA0 = fmaf(LA.w, v0[4*l4+3], sA0);
        sA1 = fmaf(LA.x, v1[4*l4+0], sA1); sA1 = fmaf(LA.y, v1[4*l4+1], sA1);
        sA1 = fmaf(LA.z, v1[4*l4+2], sA1); sA1 = fmaf(LA.w, v1[4*l4+3], sA1);
        sB0 = fmaf(LB.x, v0[4*l4+0], sB0); sB0 = fmaf(LB.y, v0[4*l4+1], sB0);
        sB0 = fmaf(LB.z, v0[4*l4+2], sB0); sB0 = fmaf(LB.w, v0[4*l4+3], sB0);
        sB1 = fmaf(LB.x, v1[4*l4+0], sB1); sB1 = fmaf(LB.y, v1[4*l4+1], sB1);
        sB1 = fmaf(LB.z, v1[4*l4+2], sB1); sB1 = fmaf(LB.w, v1[4*l4+3], sB1);
    }
    float acc0 = fmaf(uA0, sA0, uB0 * sB0);
    float acc1 = fmaf(uA1, sA1, uB1 * sB1);

    red[oct * RPAD + bp * 8 + hwl] = make_float2(acc0, acc1);
    __syncthreads();

    // ---- 64 cells: sum 8 octant partials, clip, store
    if (t < 64) {
        int hw  = t & 7;
        int bl  = t >> 3;                 // local batch 0..7
        int bpi = bl >> 1, par = bl & 1;
        float s = 0.0f;
        #pragma unroll
        for (int o = 0; o < 8; ++o) {
            float2 r = red[o * RPAD + bpi * 8 + hw];
            s += par ? r.y : r.x;
        }
        s = fminf(fmaxf(s, 0.0f), 1.0f);
        int b = bhalf * 8 + bl;
        dst[b * (HH * WW) + h * 32 + (hw0 & 31) + hw] = s;
    }
}

extern "C" void kernel_launch(void* const* d_in, const int* in_sizes, int n_in,
                              void* d_out, int out_size, void* d_ws, size_t ws_size,
                              hipStream_t stream) {
    const float* x  = (const float*)d_in[0];   // (16,32,32)
    const float* tg = (const float*)d_in[1];   // (4,512,32,32)
    float* out = (float*)d_out;                // (16,32,32)
    float* ws  = (float*)d_ws;                 // 64 KB used

    const int grid = 256;                      // 128 spatial tiles x 2 batch halves -> 1 block/CU
    const size_t L = (size_t)NPOS * HH * WW;

    // ping-pong: x -> ws -> out -> ws -> out  (kernel boundary = coherence point)
    asic_layer<<<grid, NTHR, 0, stream>>>(x,   tg + 0 * L, ws);
    asic_layer<<<grid, NTHR, 0, stream>>>(ws,  tg + 1 * L, out);
    asic_layer<<<grid, NTHR, 0, stream>>>(out, tg + 2 * L, ws);
    asic_layer<<<grid, NTHR, 0, stream>>>(ws,  tg + 3 * L, out);
}